// Round 8
// baseline (1226.663 us; speedup 1.0000x reference)
//
#include <hip/hip_runtime.h>
#include <math.h>

#define H 64
#define W 64
#define HW 4096
#define CH 128
#define CIN 256
#define COUT 384
#define KDIM 1152
#define NB 4

typedef _Float16 f16x8 __attribute__((ext_vector_type(8)));
typedef float f32x4 __attribute__((ext_vector_type(4)));

__device__ __forceinline__ void gl_lds16(const _Float16* g, _Float16* l) {
    __builtin_amdgcn_global_load_lds(
        (const __attribute__((address_space(1))) unsigned int*)(g),
        (__attribute__((address_space(3))) unsigned int*)(l), 16, 0, 0);
}

// ---------------- copy former+latter passthrough ----------------
__global__ void copy_passthrough(const float* __restrict__ x, float* __restrict__ out) {
    int idx = blockIdx.x * blockDim.x + threadIdx.x; // over NB*CIN*HW
    if (idx >= NB * CIN * HW) return;
    int b = idx / (CIN * HW);
    int rem = idx - b * (CIN * HW);
    out[(size_t)b * COUT * HW + rem] = x[idx];
}

// ---------------- im2col of former -> P (HW x KDIM, f16), vectorized ----------------
__global__ void build_patches_f16(const float* __restrict__ former, _Float16* __restrict__ P) {
    int idx8 = blockIdx.x * blockDim.x + threadIdx.x; // over HW*144
    if (idx8 >= HW * 144) return;
    int i = idx8 / 144, k0 = (idx8 - i * 144) * 8;
    int iy = i >> 6, ix = i & 63;
    f16x8 v8;
    #pragma unroll
    for (int u = 0; u < 8; ++u) {
        int k = k0 + u;
        int c = k / 9, q = k - c * 9;
        int dy = q / 3, dx = q - dy * 3;
        int y = iy + dy - 1, x = ix + dx - 1;
        float v = 0.f;
        if ((unsigned)y < H && (unsigned)x < W) v = former[c * HW + y * W + x];
        v8[u] = (_Float16)v;
    }
    *(f16x8*)(P + (size_t)i * KDIM + k0) = v8;
}

// ---------------- normalized latter windows -> WN (f16), md = {mm, mm*den} ----------------
__global__ void build_winn_f16(const float* __restrict__ latter, const float* __restrict__ mask,
                               const int* __restrict__ mask_thred_p,
                               _Float16* __restrict__ WN, float2* __restrict__ md) {
    int j = blockIdx.x;               // patch index
    int y0 = j >> 6, x0 = j & 63;
    __shared__ float red[256];
    float vals[8];
    float ss = 0.f;
    int k0 = threadIdx.x * 8;
    bool act = (threadIdx.x < 144);
    if (act) {
        #pragma unroll
        for (int u = 0; u < 8; ++u) {
            int k = k0 + u;
            int c = k / 9, q = k - c * 9;
            int dy = q / 3, dx = q - dy * 3;
            int y = y0 + dy - 1, x = x0 + dx - 1;
            float v = 0.f;
            if ((unsigned)y < H && (unsigned)x < W) v = latter[c * HW + y * W + x];
            vals[u] = v;
            ss += v * v;
        }
    }
    red[threadIdx.x] = ss;
    __syncthreads();
    for (int s = 128; s > 0; s >>= 1) {
        if (threadIdx.x < s) red[threadIdx.x] += red[threadIdx.x + s];
        __syncthreads();
    }
    float d = fmaxf(sqrtf(red[0]), 1e-4f);
    float inv = 1.f / d;
    if (act) {
        f16x8 w8;
        #pragma unroll
        for (int u = 0; u < 8; ++u) w8[u] = (_Float16)(vals[u] * inv);
        *(f16x8*)(WN + (size_t)j * KDIM + k0) = w8;
    }
    if (threadIdx.x == 0) {
        float s = 0.f;
        for (int q = 0; q < 9; ++q) {
            int dy = q / 3, dx = q - dy * 3;
            int y = y0 + dy - 1, x = x0 + dx - 1;
            if ((unsigned)y < H && (unsigned)x < W) s += mask[y * W + x];
        }
        float mmean = s / 9.f;
        float thr = (float)mask_thred_p[0] / 9.f;
        float m = (mmean <= thr) ? 1.f : 0.f;
        md[j] = make_float2(m, m * d);
    }
}

// ---------------- GEMM1: MFMA f16 NT, 128x128 tile, BK=64, XOR LDS, f16 out ----------------
__launch_bounds__(256)
__global__ void gemm_f16_nt(const _Float16* __restrict__ A, const _Float16* __restrict__ B,
                            _Float16* __restrict__ C, int K, int ldc) {
    __shared__ _Float16 As[128 * 64];
    __shared__ _Float16 Bs[128 * 64];
    int tid = threadIdx.x;
    int wave = tid >> 6, lane = tid & 63;
    int quad = lane >> 4, lr = lane & 15;
    int wr = wave >> 1, wc = wave & 1;
    int i0 = blockIdx.y * 128, j0 = blockIdx.x * 128;

    int r0 = tid >> 3;                       // 0..31
    int lk = ((tid & 7) ^ ((tid >> 3) & 7)) * 8;

    f32x4 acc[4][4];
    #pragma unroll
    for (int a = 0; a < 4; ++a)
        #pragma unroll
        for (int b = 0; b < 4; ++b) acc[a][b] = (f32x4){0.f, 0.f, 0.f, 0.f};

    const _Float16* Ab = A + (size_t)i0 * K;
    const _Float16* Bb = B + (size_t)j0 * K;

    int ra[4][2], rb[4][2];
    #pragma unroll
    for (int t = 0; t < 4; ++t) {
        int rowA = wr * 64 + t * 16 + lr;
        int rowB = wc * 64 + t * 16 + lr;
        #pragma unroll
        for (int s = 0; s < 2; ++s) {
            ra[t][s] = rowA * 64 + (((quad + 4 * s) ^ (lr & 7)) * 8);
            rb[t][s] = rowB * 64 + (((quad + 4 * s) ^ (lr & 7)) * 8);
        }
    }

    for (int k0 = 0; k0 < K; k0 += 64) {
        __syncthreads();
        #pragma unroll
        for (int j = 0; j < 4; ++j) {
            int row = r0 + j * 32;
            gl_lds16(Ab + (size_t)row * K + k0 + lk, As + (tid + j * 256) * 8);
            gl_lds16(Bb + (size_t)row * K + k0 + lk, Bs + (tid + j * 256) * 8);
        }
        __syncthreads();
        #pragma unroll
        for (int s = 0; s < 2; ++s) {
            f16x8 af[4], bfr[4];
            #pragma unroll
            for (int mi = 0; mi < 4; ++mi) af[mi] = *(const f16x8*)(As + ra[mi][s]);
            #pragma unroll
            for (int ni = 0; ni < 4; ++ni) bfr[ni] = *(const f16x8*)(Bs + rb[ni][s]);
            #pragma unroll
            for (int mi = 0; mi < 4; ++mi)
                #pragma unroll
                for (int ni = 0; ni < 4; ++ni)
                    acc[mi][ni] = __builtin_amdgcn_mfma_f32_16x16x32_f16(af[mi], bfr[ni], acc[mi][ni], 0, 0, 0);
        }
    }

    #pragma unroll
    for (int mi = 0; mi < 4; ++mi) {
        #pragma unroll
        for (int r = 0; r < 4; ++r) {
            int row = i0 + wr * 64 + mi * 16 + quad * 4 + r;
            _Float16* Cr = C + (size_t)row * ldc + j0 + wc * 64 + lr;
            #pragma unroll
            for (int ni = 0; ni < 4; ++ni)
                Cr[ni * 16] = (_Float16)acc[mi][ni][r];
        }
    }
}

// ---------------- GEMM2: MFMA f16 NT, 128x128 tile, K-split 2 (blockIdx.z), fp32 out ----------------
__launch_bounds__(256)
__global__ void gemm2_f16_nt(const _Float16* __restrict__ A, const _Float16* __restrict__ B,
                             float* __restrict__ C, int K, int ldc) {
    __shared__ _Float16 As[128 * 64];
    __shared__ _Float16 Bs[128 * 64];
    int tid = threadIdx.x;
    int wave = tid >> 6, lane = tid & 63;
    int quad = lane >> 4, lr = lane & 15;
    int wr = wave >> 1, wc = wave & 1;
    int i0 = blockIdx.y * 128, j0 = blockIdx.x * 128;
    int kz0 = blockIdx.z * (K >> 1), kz1 = kz0 + (K >> 1);
    float* Cz = C + (size_t)blockIdx.z * KDIM * HW;

    int r0 = tid >> 3;
    int lk = ((tid & 7) ^ ((tid >> 3) & 7)) * 8;

    f32x4 acc[4][4];
    #pragma unroll
    for (int a = 0; a < 4; ++a)
        #pragma unroll
        for (int b = 0; b < 4; ++b) acc[a][b] = (f32x4){0.f, 0.f, 0.f, 0.f};

    const _Float16* Ab = A + (size_t)i0 * K;
    const _Float16* Bb = B + (size_t)j0 * K;

    int ra[4][2], rb[4][2];
    #pragma unroll
    for (int t = 0; t < 4; ++t) {
        int rowA = wr * 64 + t * 16 + lr;
        int rowB = wc * 64 + t * 16 + lr;
        #pragma unroll
        for (int s = 0; s < 2; ++s) {
            ra[t][s] = rowA * 64 + (((quad + 4 * s) ^ (lr & 7)) * 8);
            rb[t][s] = rowB * 64 + (((quad + 4 * s) ^ (lr & 7)) * 8);
        }
    }

    for (int k0 = kz0; k0 < kz1; k0 += 64) {
        __syncthreads();
        #pragma unroll
        for (int j = 0; j < 4; ++j) {
            int row = r0 + j * 32;
            gl_lds16(Ab + (size_t)row * K + k0 + lk, As + (tid + j * 256) * 8);
            gl_lds16(Bb + (size_t)row * K + k0 + lk, Bs + (tid + j * 256) * 8);
        }
        __syncthreads();
        #pragma unroll
        for (int s = 0; s < 2; ++s) {
            f16x8 af[4], bfr[4];
            #pragma unroll
            for (int mi = 0; mi < 4; ++mi) af[mi] = *(const f16x8*)(As + ra[mi][s]);
            #pragma unroll
            for (int ni = 0; ni < 4; ++ni) bfr[ni] = *(const f16x8*)(Bs + rb[ni][s]);
            #pragma unroll
            for (int mi = 0; mi < 4; ++mi)
                #pragma unroll
                for (int ni = 0; ni < 4; ++ni)
                    acc[mi][ni] = __builtin_amdgcn_mfma_f32_16x16x32_f16(af[mi], bfr[ni], acc[mi][ni], 0, 0, 0);
        }
    }

    #pragma unroll
    for (int mi = 0; mi < 4; ++mi) {
        #pragma unroll
        for (int r = 0; r < 4; ++r) {
            int row = i0 + wr * 64 + mi * 16 + quad * 4 + r;
            float* Cr = Cz + (size_t)row * ldc + j0 + wc * 64 + lr;
            #pragma unroll
            for (int ni = 0; ni < 4; ++ni)
                Cr[ni * 16] = acc[mi][ni][r];
        }
    }
}

// ---------------- pass A: 2 output rows/block, 512 thr, f16 in/out, XOR LDS ----------------
__launch_bounds__(512)
__global__ void diag_perm2(const _Float16* __restrict__ S, _Float16* __restrict__ E1) {
    int bid = blockIdx.x;                        // 0..2047
    int pair = (bid & 7) * 256 + (bid >> 3);     // XCD-contiguous p ranges
    int p0 = pair * 2;
    int tid = threadIdx.x;
    __shared__ float lds[4][64 * 64];            // 64 KB
    for (int rr = 0; rr < 4; ++rr) {
        int pr = p0 + rr - 1;
        bool v = (unsigned)pr < HW;
        const f16x8* Sr = (const f16x8*)(S + (size_t)pr * HW);
        f16x8 val = v ? Sr[tid] : (f16x8){0, 0, 0, 0, 0, 0, 0, 0};
        int j = tid * 8;
        #pragma unroll
        for (int u = 0; u < 8; ++u) {
            int jj = j + u;
            lds[rr][((jj & 63) << 6) | ((jj >> 6) ^ (jj & 63))] = (float)val[u];
        }
    }
    __syncthreads();
    #pragma unroll
    for (int po = 0; po < 2; ++po) {
        int p = p0 + po;
        int g = ((p & 63) << 6) | (p >> 6);      // rm(p)
        _Float16* Eg = E1 + (size_t)g * HW;
        int h0 = tid * 8;
        f16x8 out;
        #pragma unroll
        for (int u = 0; u < 8; ++u) {
            int h = h0 + u;
            int q = ((h & 63) << 6) | (h >> 6);  // rm(h)
            float s = 0.f;
            #pragma unroll
            for (int d1 = -1; d1 <= 1; ++d1) {
                int pp = p + d1, qq = q + d1;
                if ((unsigned)pp < HW && (unsigned)qq < HW)
                    s += lds[po + d1 + 1][((qq & 63) << 6) | ((qq >> 6) ^ (qq & 63))];
            }
            out[u] = (_Float16)s;
        }
        *(f16x8*)(Eg + h0) = out;
    }
}

// ---------------- pass B: D2 = diagbox3(E1); softmax over h; *mm*den; f16 out ----------------
__launch_bounds__(512)
__global__ void diag_softmax(const _Float16* __restrict__ E1, const float2* __restrict__ md,
                             _Float16* __restrict__ YB) {
    int g = (blockIdx.x & 7) * 512 + (blockIdx.x >> 3);   // XCD-contiguous g ranges
    int tid = threadIdx.x;
    int h0 = tid * 8;
    __shared__ float red[512];
    float D[8] = {0.f, 0.f, 0.f, 0.f, 0.f, 0.f, 0.f, 0.f};
    #pragma unroll
    for (int d2 = -1; d2 <= 1; ++d2) {
        int gg = g + d2;
        if ((unsigned)gg >= HW) continue;
        const _Float16* Er = E1 + (size_t)gg * HW;
        float w[10];  // covers indices h0-1 .. h0+8
        f16x8 m8 = *(const f16x8*)(Er + h0);
        #pragma unroll
        for (int u = 0; u < 8; ++u) w[u + 1] = (float)m8[u];
        w[0] = (h0 > 0) ? (float)Er[h0 - 1] : 0.f;
        w[9] = (h0 + 8 < HW) ? (float)Er[h0 + 8] : 0.f;
        #pragma unroll
        for (int u = 0; u < 8; ++u) {
            int hh = h0 + u + d2;
            if ((unsigned)hh < HW) D[u] += w[u + d2 + 1];
        }
    }
    float lv[8], sv[8];
    float lmax = -1e30f;
    #pragma unroll
    for (int u = 0; u < 8; ++u) {
        int h = h0 + u;
        int j = ((h & 63) << 6) | (h >> 6);  // rm(h)
        float2 m2 = md[j];
        float l = 10.f * D[u] * m2.x;
        lv[u] = l;
        sv[u] = m2.y;
        lmax = fmaxf(lmax, l);
    }
    red[tid] = lmax;
    __syncthreads();
    for (int s = 256; s > 0; s >>= 1) {
        if (tid < s) red[tid] = fmaxf(red[tid], red[tid + s]);
        __syncthreads();
    }
    float M = red[0];
    __syncthreads();
    float ev[8];
    float ssum = 0.f;
    #pragma unroll
    for (int u = 0; u < 8; ++u) {
        ev[u] = expf(lv[u] - M);
        ssum += ev[u];
    }
    red[tid] = ssum;
    __syncthreads();
    for (int s = 256; s > 0; s >>= 1) {
        if (tid < s) red[tid] += red[tid + s];
        __syncthreads();
    }
    float inv = 1.f / red[0];
    f16x8 outv;
    #pragma unroll
    for (int u = 0; u < 8; ++u)
        outv[u] = (_Float16)(ev[u] * inv * sv[u]);
    *(f16x8*)(YB + (size_t)g * HW + h0) = outv;
}

// ---------------- WNT[n, h] = WN[rm(h)][n]  (f16, K-contiguous for GEMM2) ----------------
__launch_bounds__(256)
__global__ void wnt_transpose(const _Float16* __restrict__ WN, _Float16* __restrict__ WNT) {
    int bx = blockIdx.x;  // h-tile: h = bx*64 + l -> j = l*64 + bx
    int by = blockIdx.y;  // n-tile
    int n0 = by * 64;
    __shared__ unsigned short tile[64][72];
    for (int c = threadIdx.x; c < 512; c += 256) {
        int l = c >> 3, seg = c & 7;
        int j = l * 64 + bx;
        uint4 v = *(const uint4*)(WN + (size_t)j * KDIM + n0 + seg * 8);
        *(uint4*)&tile[l][seg * 8] = v;
    }
    __syncthreads();
    for (int c = threadIdx.x; c < 512; c += 256) {
        int r = c >> 3, seg = c & 7;
        unsigned short tmp[8];
        #pragma unroll
        for (int u = 0; u < 8; ++u) tmp[u] = tile[seg * 8 + u][r];
        *(uint4*)(WNT + (size_t)(n0 + r) * HW + bx * 64 + seg * 8) = *(uint4*)tmp;
    }
}

// ---------------- fold C2T partials (2 x KDIM x HW, cols g = x*64+y) into shift output ----------------
__launch_bounds__(256)
__global__ void fold_out_t(const float* __restrict__ Ca, const float* __restrict__ Cb,
                           float* __restrict__ outb) {
    int c = blockIdx.x;
    __shared__ float lds[64 * 65];
    const float* basea = Ca + (size_t)c * 9 * HW;
    const float* baseb = Cb + (size_t)c * 9 * HW;
    #pragma unroll 4
    for (int t = 0; t < 16; ++t) {
        int pos = threadIdx.x + t * 256;
        int x = pos >> 6, y = pos & 63;
        float s = 0.f;
        #pragma unroll
        for (int dy = 0; dy < 3; ++dy) {
            int yy = y + 1 - dy;
            if ((unsigned)yy >= 64) continue;
            #pragma unroll
            for (int dx = 0; dx < 3; ++dx) {
                int xx = x + 1 - dx;
                if ((unsigned)xx >= 64) continue;
                size_t off = (size_t)(dy * 3 + dx) * HW + xx * 64 + yy;
                s += basea[off] + baseb[off];
            }
        }
        lds[y * 65 + x] = s * (1.f / 9.f);
    }
    __syncthreads();
    #pragma unroll 4
    for (int t = 0; t < 16; ++t) {
        int pix = threadIdx.x + t * 256;
        outb[(size_t)(CIN + c) * HW + pix] = lds[(pix >> 6) * 65 + (pix & 63)];
    }
}

extern "C" void kernel_launch(void* const* d_in, const int* in_sizes, int n_in,
                              void* d_out, int out_size, void* d_ws, size_t ws_size,
                              hipStream_t stream) {
    const float* x = (const float*)d_in[0];
    const float* mask = (const float*)d_in[1];
    const int* mask_thred = (const int*)d_in[3];
    float* out = (float*)d_out;

    char* ws = (char*)d_ws;
    _Float16* P  = (_Float16*)(ws);                       //  9,437,184 B
    _Float16* WN = (_Float16*)(ws + 9437184);             //  9,437,184 B
    _Float16* S  = (_Float16*)(ws + 18874368);            // 33,554,432 B (f16)
    _Float16* E1 = (_Float16*)(ws + 52428800);            // 33,554,432 B (f16)
    float*  C2T  = (float*)(ws + 85983232);               // 2 x 18,874,368 B
    float2* md   = (float2*)(ws + 123731968);             // 32,768 B
    // aliases (lifetimes disjoint): YB over S; WNT over E1
    _Float16* YB  = S;
    _Float16* WNT = E1;
    float* C2Ta = C2T;
    float* C2Tb = C2T + (size_t)KDIM * HW;

    copy_passthrough<<<(NB * CIN * HW + 255) / 256, 256, 0, stream>>>(x, out);

    for (int b = 0; b < NB; ++b) {
        const float* xb = x + (size_t)b * CIN * HW;
        const float* former = xb;
        const float* latter = xb + (size_t)CH * HW;
        const float* maskb = mask + (size_t)b * HW;
        float* outb = out + (size_t)b * COUT * HW;

        build_patches_f16<<<(HW * 144 + 255) / 256, 256, 0, stream>>>(former, P);
        build_winn_f16<<<HW, 256, 0, stream>>>(latter, maskb, mask_thred, WN, md);
        gemm_f16_nt<<<dim3(32, 32), 256, 0, stream>>>(P, WN, S, KDIM, HW);
        diag_perm2<<<HW / 2, 512, 0, stream>>>(S, E1);
        diag_softmax<<<HW, 512, 0, stream>>>(E1, md, YB);
        wnt_transpose<<<dim3(64, KDIM / 64), 256, 0, stream>>>(WN, WNT);
        // C2T[z][n][g] = sum_{h in half z} WNT[n][h] * YB[g][h]
        gemm2_f16_nt<<<dim3(32, KDIM / 128, 2), 256, 0, stream>>>(WNT, YB, C2T, HW, HW);
        fold_out_t<<<CH, 256, 0, stream>>>(C2Ta, C2Tb, outb);
    }
}

// Round 9
// 1144.162 us; speedup vs baseline: 1.0721x; 1.0721x over previous
//
#include <hip/hip_runtime.h>
#include <math.h>

#define H 64
#define W 64
#define HW 4096
#define CH 128
#define CIN 256
#define COUT 384
#define KDIM 1152
#define NB 4

typedef _Float16 f16x8 __attribute__((ext_vector_type(8)));
typedef float f32x4 __attribute__((ext_vector_type(4)));

__device__ __forceinline__ void gl_lds16(const _Float16* g, _Float16* l) {
    __builtin_amdgcn_global_load_lds(
        (const __attribute__((address_space(1))) unsigned int*)(g),
        (__attribute__((address_space(3))) unsigned int*)(l), 16, 0, 0);
}

// ---------------- copy former+latter passthrough ----------------
__global__ void copy_passthrough(const float* __restrict__ x, float* __restrict__ out) {
    int idx = blockIdx.x * blockDim.x + threadIdx.x; // over NB*CIN*HW
    if (idx >= NB * CIN * HW) return;
    int b = idx / (CIN * HW);
    int rem = idx - b * (CIN * HW);
    out[(size_t)b * COUT * HW + rem] = x[idx];
}

// ---------------- im2col of former -> P (HW x KDIM, f16), vectorized ----------------
__global__ void build_patches_f16(const float* __restrict__ former, _Float16* __restrict__ P) {
    int idx8 = blockIdx.x * blockDim.x + threadIdx.x; // over HW*144
    if (idx8 >= HW * 144) return;
    int i = idx8 / 144, k0 = (idx8 - i * 144) * 8;
    int iy = i >> 6, ix = i & 63;
    f16x8 v8;
    #pragma unroll
    for (int u = 0; u < 8; ++u) {
        int k = k0 + u;
        int c = k / 9, q = k - c * 9;
        int dy = q / 3, dx = q - dy * 3;
        int y = iy + dy - 1, x = ix + dx - 1;
        float v = 0.f;
        if ((unsigned)y < H && (unsigned)x < W) v = former[c * HW + y * W + x];
        v8[u] = (_Float16)v;
    }
    *(f16x8*)(P + (size_t)i * KDIM + k0) = v8;
}

// ---------------- normalized latter windows -> WN (f16), md = {mm, mm*den} ----------------
__global__ void build_winn_f16(const float* __restrict__ latter, const float* __restrict__ mask,
                               const int* __restrict__ mask_thred_p,
                               _Float16* __restrict__ WN, float2* __restrict__ md) {
    int j = blockIdx.x;               // patch index
    int y0 = j >> 6, x0 = j & 63;
    __shared__ float red[256];
    float vals[8];
    float ss = 0.f;
    int k0 = threadIdx.x * 8;
    bool act = (threadIdx.x < 144);
    if (act) {
        #pragma unroll
        for (int u = 0; u < 8; ++u) {
            int k = k0 + u;
            int c = k / 9, q = k - c * 9;
            int dy = q / 3, dx = q - dy * 3;
            int y = y0 + dy - 1, x = x0 + dx - 1;
            float v = 0.f;
            if ((unsigned)y < H && (unsigned)x < W) v = latter[c * HW + y * W + x];
            vals[u] = v;
            ss += v * v;
        }
    }
    red[threadIdx.x] = ss;
    __syncthreads();
    for (int s = 128; s > 0; s >>= 1) {
        if (threadIdx.x < s) red[threadIdx.x] += red[threadIdx.x + s];
        __syncthreads();
    }
    float d = fmaxf(sqrtf(red[0]), 1e-4f);
    float inv = 1.f / d;
    if (act) {
        f16x8 w8;
        #pragma unroll
        for (int u = 0; u < 8; ++u) w8[u] = (_Float16)(vals[u] * inv);
        *(f16x8*)(WN + (size_t)j * KDIM + k0) = w8;
    }
    if (threadIdx.x == 0) {
        float s = 0.f;
        for (int q = 0; q < 9; ++q) {
            int dy = q / 3, dx = q - dy * 3;
            int y = y0 + dy - 1, x = x0 + dx - 1;
            if ((unsigned)y < H && (unsigned)x < W) s += mask[y * W + x];
        }
        float mmean = s / 9.f;
        float thr = (float)mask_thred_p[0] / 9.f;
        float m = (mmean <= thr) ? 1.f : 0.f;
        md[j] = make_float2(m, m * d);
    }
}

// ---------------- GEMM1: MFMA f16 NT, 128x128 tile, BK=64, XOR LDS, f16 out ----------------
__launch_bounds__(256)
__global__ void gemm_f16_nt(const _Float16* __restrict__ A, const _Float16* __restrict__ B,
                            _Float16* __restrict__ C, int K, int ldc) {
    __shared__ _Float16 As[128 * 64];
    __shared__ _Float16 Bs[128 * 64];
    int tid = threadIdx.x;
    int wave = tid >> 6, lane = tid & 63;
    int quad = lane >> 4, lr = lane & 15;
    int wr = wave >> 1, wc = wave & 1;
    int i0 = blockIdx.y * 128, j0 = blockIdx.x * 128;

    int r0 = tid >> 3;                       // 0..31
    int lk = ((tid & 7) ^ ((tid >> 3) & 7)) * 8;

    f32x4 acc[4][4];
    #pragma unroll
    for (int a = 0; a < 4; ++a)
        #pragma unroll
        for (int b = 0; b < 4; ++b) acc[a][b] = (f32x4){0.f, 0.f, 0.f, 0.f};

    const _Float16* Ab = A + (size_t)i0 * K;
    const _Float16* Bb = B + (size_t)j0 * K;

    int ra[4][2], rb[4][2];
    #pragma unroll
    for (int t = 0; t < 4; ++t) {
        int rowA = wr * 64 + t * 16 + lr;
        int rowB = wc * 64 + t * 16 + lr;
        #pragma unroll
        for (int s = 0; s < 2; ++s) {
            ra[t][s] = rowA * 64 + (((quad + 4 * s) ^ (lr & 7)) * 8);
            rb[t][s] = rowB * 64 + (((quad + 4 * s) ^ (lr & 7)) * 8);
        }
    }

    for (int k0 = 0; k0 < K; k0 += 64) {
        __syncthreads();
        #pragma unroll
        for (int j = 0; j < 4; ++j) {
            int row = r0 + j * 32;
            gl_lds16(Ab + (size_t)row * K + k0 + lk, As + (tid + j * 256) * 8);
            gl_lds16(Bb + (size_t)row * K + k0 + lk, Bs + (tid + j * 256) * 8);
        }
        __syncthreads();
        #pragma unroll
        for (int s = 0; s < 2; ++s) {
            f16x8 af[4], bfr[4];
            #pragma unroll
            for (int mi = 0; mi < 4; ++mi) af[mi] = *(const f16x8*)(As + ra[mi][s]);
            #pragma unroll
            for (int ni = 0; ni < 4; ++ni) bfr[ni] = *(const f16x8*)(Bs + rb[ni][s]);
            #pragma unroll
            for (int mi = 0; mi < 4; ++mi)
                #pragma unroll
                for (int ni = 0; ni < 4; ++ni)
                    acc[mi][ni] = __builtin_amdgcn_mfma_f32_16x16x32_f16(af[mi], bfr[ni], acc[mi][ni], 0, 0, 0);
        }
    }

    #pragma unroll
    for (int mi = 0; mi < 4; ++mi) {
        #pragma unroll
        for (int r = 0; r < 4; ++r) {
            int row = i0 + wr * 64 + mi * 16 + quad * 4 + r;
            _Float16* Cr = C + (size_t)row * ldc + j0 + wc * 64 + lr;
            #pragma unroll
            for (int ni = 0; ni < 4; ++ni)
                Cr[ni * 16] = (_Float16)acc[mi][ni][r];
        }
    }
}

// ---------------- GEMM2: MFMA f16 NT, 128(M)x64(N) tile, BK=64, full K, fp32 out ----------------
__launch_bounds__(256)
__global__ void gemm2_f16_nt(const _Float16* __restrict__ A, const _Float16* __restrict__ B,
                             float* __restrict__ C, int K, int ldc) {
    __shared__ _Float16 As[128 * 64];
    __shared__ _Float16 Bs[64 * 64];
    int tid = threadIdx.x;
    int wave = tid >> 6, lane = tid & 63;
    int quad = lane >> 4, lr = lane & 15;
    int wr = wave >> 1, wc = wave & 1;
    int i0 = blockIdx.y * 128, j0 = blockIdx.x * 64;

    int r0 = tid >> 3;
    int lk = ((tid & 7) ^ ((tid >> 3) & 7)) * 8;

    f32x4 acc[4][2];
    #pragma unroll
    for (int a = 0; a < 4; ++a)
        #pragma unroll
        for (int b = 0; b < 2; ++b) acc[a][b] = (f32x4){0.f, 0.f, 0.f, 0.f};

    const _Float16* Ab = A + (size_t)i0 * K;
    const _Float16* Bb = B + (size_t)j0 * K;

    int ra[4][2], rb[2][2];
    #pragma unroll
    for (int t = 0; t < 4; ++t) {
        int rowA = wr * 64 + t * 16 + lr;
        #pragma unroll
        for (int s = 0; s < 2; ++s)
            ra[t][s] = rowA * 64 + (((quad + 4 * s) ^ (lr & 7)) * 8);
    }
    #pragma unroll
    for (int t = 0; t < 2; ++t) {
        int rowB = wc * 32 + t * 16 + lr;
        #pragma unroll
        for (int s = 0; s < 2; ++s)
            rb[t][s] = rowB * 64 + (((quad + 4 * s) ^ (lr & 7)) * 8);
    }

    for (int k0 = 0; k0 < K; k0 += 64) {
        __syncthreads();
        #pragma unroll
        for (int j = 0; j < 4; ++j) {
            int row = r0 + j * 32;
            gl_lds16(Ab + (size_t)row * K + k0 + lk, As + (tid + j * 256) * 8);
        }
        #pragma unroll
        for (int j = 0; j < 2; ++j) {
            int row = r0 + j * 32;
            gl_lds16(Bb + (size_t)row * K + k0 + lk, Bs + (tid + j * 256) * 8);
        }
        __syncthreads();
        #pragma unroll
        for (int s = 0; s < 2; ++s) {
            f16x8 af[4], bfr[2];
            #pragma unroll
            for (int mi = 0; mi < 4; ++mi) af[mi] = *(const f16x8*)(As + ra[mi][s]);
            #pragma unroll
            for (int ni = 0; ni < 2; ++ni) bfr[ni] = *(const f16x8*)(Bs + rb[ni][s]);
            #pragma unroll
            for (int mi = 0; mi < 4; ++mi)
                #pragma unroll
                for (int ni = 0; ni < 2; ++ni)
                    acc[mi][ni] = __builtin_amdgcn_mfma_f32_16x16x32_f16(af[mi], bfr[ni], acc[mi][ni], 0, 0, 0);
        }
    }

    #pragma unroll
    for (int mi = 0; mi < 4; ++mi) {
        #pragma unroll
        for (int r = 0; r < 4; ++r) {
            int row = i0 + wr * 64 + mi * 16 + quad * 4 + r;
            float* Cr = C + (size_t)row * ldc + j0 + wc * 32 + lr;
            #pragma unroll
            for (int ni = 0; ni < 2; ++ni)
                Cr[ni * 16] = acc[mi][ni][r];
        }
    }
}

// ---------------- pass A: 2 output rows/block, 512 thr, f16 in/out, XOR LDS ----------------
__launch_bounds__(512)
__global__ void diag_perm2(const _Float16* __restrict__ S, _Float16* __restrict__ E1) {
    int bid = blockIdx.x;                        // 0..2047
    int pair = (bid & 7) * 256 + (bid >> 3);     // XCD-contiguous p ranges
    int p0 = pair * 2;
    int tid = threadIdx.x;
    __shared__ float lds[4][64 * 64];            // 64 KB
    for (int rr = 0; rr < 4; ++rr) {
        int pr = p0 + rr - 1;
        bool v = (unsigned)pr < HW;
        const f16x8* Sr = (const f16x8*)(S + (size_t)pr * HW);
        f16x8 val = v ? Sr[tid] : (f16x8){0, 0, 0, 0, 0, 0, 0, 0};
        int j = tid * 8;
        #pragma unroll
        for (int u = 0; u < 8; ++u) {
            int jj = j + u;
            lds[rr][((jj & 63) << 6) | ((jj >> 6) ^ (jj & 63))] = (float)val[u];
        }
    }
    __syncthreads();
    #pragma unroll
    for (int po = 0; po < 2; ++po) {
        int p = p0 + po;
        int g = ((p & 63) << 6) | (p >> 6);      // rm(p)
        _Float16* Eg = E1 + (size_t)g * HW;
        int h0 = tid * 8;
        f16x8 out;
        #pragma unroll
        for (int u = 0; u < 8; ++u) {
            int h = h0 + u;
            int q = ((h & 63) << 6) | (h >> 6);  // rm(h)
            float s = 0.f;
            #pragma unroll
            for (int d1 = -1; d1 <= 1; ++d1) {
                int pp = p + d1, qq = q + d1;
                if ((unsigned)pp < HW && (unsigned)qq < HW)
                    s += lds[po + d1 + 1][((qq & 63) << 6) | ((qq >> 6) ^ (qq & 63))];
            }
            out[u] = (_Float16)s;
        }
        *(f16x8*)(Eg + h0) = out;
    }
}

// ---------------- pass B: D2 = diagbox3(E1); softmax over h; *mm*den; f16 out ----------------
__launch_bounds__(512)
__global__ void diag_softmax(const _Float16* __restrict__ E1, const float2* __restrict__ md,
                             _Float16* __restrict__ YB) {
    int g = (blockIdx.x & 7) * 512 + (blockIdx.x >> 3);   // XCD-contiguous g ranges
    int tid = threadIdx.x;
    int h0 = tid * 8;
    __shared__ float red[512];
    float D[8] = {0.f, 0.f, 0.f, 0.f, 0.f, 0.f, 0.f, 0.f};
    #pragma unroll
    for (int d2 = -1; d2 <= 1; ++d2) {
        int gg = g + d2;
        if ((unsigned)gg >= HW) continue;
        const _Float16* Er = E1 + (size_t)gg * HW;
        float w[10];  // covers indices h0-1 .. h0+8
        f16x8 m8 = *(const f16x8*)(Er + h0);
        #pragma unroll
        for (int u = 0; u < 8; ++u) w[u + 1] = (float)m8[u];
        w[0] = (h0 > 0) ? (float)Er[h0 - 1] : 0.f;
        w[9] = (h0 + 8 < HW) ? (float)Er[h0 + 8] : 0.f;
        #pragma unroll
        for (int u = 0; u < 8; ++u) {
            int hh = h0 + u + d2;
            if ((unsigned)hh < HW) D[u] += w[u + d2 + 1];
        }
    }
    float lv[8], sv[8];
    float lmax = -1e30f;
    #pragma unroll
    for (int u = 0; u < 8; ++u) {
        int h = h0 + u;
        int j = ((h & 63) << 6) | (h >> 6);  // rm(h)
        float2 m2 = md[j];
        float l = 10.f * D[u] * m2.x;
        lv[u] = l;
        sv[u] = m2.y;
        lmax = fmaxf(lmax, l);
    }
    red[tid] = lmax;
    __syncthreads();
    for (int s = 256; s > 0; s >>= 1) {
        if (tid < s) red[tid] = fmaxf(red[tid], red[tid + s]);
        __syncthreads();
    }
    float M = red[0];
    __syncthreads();
    float ev[8];
    float ssum = 0.f;
    #pragma unroll
    for (int u = 0; u < 8; ++u) {
        ev[u] = expf(lv[u] - M);
        ssum += ev[u];
    }
    red[tid] = ssum;
    __syncthreads();
    for (int s = 256; s > 0; s >>= 1) {
        if (tid < s) red[tid] += red[tid + s];
        __syncthreads();
    }
    float inv = 1.f / red[0];
    f16x8 outv;
    #pragma unroll
    for (int u = 0; u < 8; ++u)
        outv[u] = (_Float16)(ev[u] * inv * sv[u]);
    *(f16x8*)(YB + (size_t)g * HW + h0) = outv;
}

// ---------------- WNT[n, h] = WN[rm(h)][n]  (f16, K-contiguous for GEMM2) ----------------
__launch_bounds__(256)
__global__ void wnt_transpose(const _Float16* __restrict__ WN, _Float16* __restrict__ WNT) {
    int bx = blockIdx.x;  // h-tile: h = bx*64 + l -> j = l*64 + bx
    int by = blockIdx.y;  // n-tile
    int n0 = by * 64;
    __shared__ unsigned short tile[64][72];
    for (int c = threadIdx.x; c < 512; c += 256) {
        int l = c >> 3, seg = c & 7;
        int j = l * 64 + bx;
        uint4 v = *(const uint4*)(WN + (size_t)j * KDIM + n0 + seg * 8);
        *(uint4*)&tile[l][seg * 8] = v;
    }
    __syncthreads();
    for (int c = threadIdx.x; c < 512; c += 256) {
        int r = c >> 3, seg = c & 7;
        unsigned short tmp[8];
        #pragma unroll
        for (int u = 0; u < 8; ++u) tmp[u] = tile[seg * 8 + u][r];
        *(uint4*)(WNT + (size_t)(n0 + r) * HW + bx * 64 + seg * 8) = *(uint4*)tmp;
    }
}

// ---------------- fold C2T (KDIM x HW, cols g = x*64+y) into shift output ----------------
__launch_bounds__(256)
__global__ void fold_out_t(const float* __restrict__ C2T, float* __restrict__ outb) {
    int c = blockIdx.x;
    __shared__ float lds[64 * 65];
    const float* base = C2T + (size_t)c * 9 * HW;
    #pragma unroll 4
    for (int t = 0; t < 16; ++t) {
        int pos = threadIdx.x + t * 256;
        int x = pos >> 6, y = pos & 63;
        float s = 0.f;
        #pragma unroll
        for (int dy = 0; dy < 3; ++dy) {
            int yy = y + 1 - dy;
            if ((unsigned)yy >= 64) continue;
            #pragma unroll
            for (int dx = 0; dx < 3; ++dx) {
                int xx = x + 1 - dx;
                if ((unsigned)xx >= 64) continue;
                s += base[(size_t)(dy * 3 + dx) * HW + xx * 64 + yy];
            }
        }
        lds[y * 65 + x] = s * (1.f / 9.f);
    }
    __syncthreads();
    #pragma unroll 4
    for (int t = 0; t < 16; ++t) {
        int pix = threadIdx.x + t * 256;
        outb[(size_t)(CIN + c) * HW + pix] = lds[(pix >> 6) * 65 + (pix & 63)];
    }
}

extern "C" void kernel_launch(void* const* d_in, const int* in_sizes, int n_in,
                              void* d_out, int out_size, void* d_ws, size_t ws_size,
                              hipStream_t stream) {
    const float* x = (const float*)d_in[0];
    const float* mask = (const float*)d_in[1];
    const int* mask_thred = (const int*)d_in[3];
    float* out = (float*)d_out;

    char* ws = (char*)d_ws;
    _Float16* P  = (_Float16*)(ws);                       //  9,437,184 B
    _Float16* WN = (_Float16*)(ws + 9437184);             //  9,437,184 B
    _Float16* S  = (_Float16*)(ws + 18874368);            // 33,554,432 B (f16)
    _Float16* E1 = (_Float16*)(ws + 52428800);            // 33,554,432 B (f16)
    float*  C2T  = (float*)(ws + 85983232);               // 18,874,368 B
    float2* md   = (float2*)(ws + 104857600);             // 32,768 B
    // aliases (lifetimes disjoint): YB over S; WNT over E1
    _Float16* YB  = S;
    _Float16* WNT = E1;

    copy_passthrough<<<(NB * CIN * HW + 255) / 256, 256, 0, stream>>>(x, out);

    for (int b = 0; b < NB; ++b) {
        const float* xb = x + (size_t)b * CIN * HW;
        const float* former = xb;
        const float* latter = xb + (size_t)CH * HW;
        const float* maskb = mask + (size_t)b * HW;
        float* outb = out + (size_t)b * COUT * HW;

        build_patches_f16<<<(HW * 144 + 255) / 256, 256, 0, stream>>>(former, P);
        build_winn_f16<<<HW, 256, 0, stream>>>(latter, maskb, mask_thred, WN, md);
        gemm_f16_nt<<<dim3(32, 32), 256, 0, stream>>>(P, WN, S, KDIM, HW);
        diag_perm2<<<HW / 2, 512, 0, stream>>>(S, E1);
        diag_softmax<<<HW, 512, 0, stream>>>(E1, md, YB);
        wnt_transpose<<<dim3(64, KDIM / 64), 256, 0, stream>>>(WN, WNT);
        // C2T[n][g] = sum_h WNT[n][h] * YB[g][h]  (M=1152, N=4096, K=4096)
        gemm2_f16_nt<<<dim3(64, KDIM / 128), 256, 0, stream>>>(WNT, YB, C2T, HW, HW);
        fold_out_t<<<CH, 256, 0, stream>>>(C2T, outb);
    }
}

// Round 10
// 904.147 us; speedup vs baseline: 1.3567x; 1.2655x over previous
//
#include <hip/hip_runtime.h>
#include <math.h>

#define H 64
#define W 64
#define HW 4096
#define CH 128
#define CIN 256
#define COUT 384
#define KDIM 1152
#define NB 4

typedef _Float16 f16x8 __attribute__((ext_vector_type(8)));
typedef float f32x4 __attribute__((ext_vector_type(4)));

__device__ __forceinline__ void gl_lds16(const _Float16* g, _Float16* l) {
    __builtin_amdgcn_global_load_lds(
        (const __attribute__((address_space(1))) unsigned int*)(g),
        (__attribute__((address_space(3))) unsigned int*)(l), 16, 0, 0);
}

// ---------------- copy former+latter passthrough (float4) ----------------
__global__ void copy_passthrough(const float4* __restrict__ x, float4* __restrict__ out) {
    int idx = blockIdx.x * blockDim.x + threadIdx.x; // over NB*CIN*HW/4
    if (idx >= NB * CIN * HW / 4) return;
    int b = idx / (CIN * HW / 4);
    int rem = idx - b * (CIN * HW / 4);
    out[(size_t)b * (COUT * HW / 4) + rem] = x[idx];
}

// ---------------- im2col of former -> P (HW x KDIM, f16), z = sample in pair ----------------
__global__ void build_patches_f16(const float* __restrict__ x, _Float16* __restrict__ P, int b0) {
    int idx8 = blockIdx.x * blockDim.x + threadIdx.x; // over HW*144
    if (idx8 >= HW * 144) return;
    const float* former = x + (size_t)(b0 + blockIdx.z) * CIN * HW;
    _Float16* Pz = P + (size_t)blockIdx.z * HW * KDIM;
    int i = idx8 / 144, k0 = (idx8 - i * 144) * 8;
    int iy = i >> 6, ix = i & 63;
    f16x8 v8;
    #pragma unroll
    for (int u = 0; u < 8; ++u) {
        int k = k0 + u;
        int c = k / 9, q = k - c * 9;
        int dy = q / 3, dx = q - dy * 3;
        int y = iy + dy - 1, xx = ix + dx - 1;
        float v = 0.f;
        if ((unsigned)y < H && (unsigned)xx < W) v = former[c * HW + y * W + xx];
        v8[u] = (_Float16)v;
    }
    *(f16x8*)(Pz + (size_t)i * KDIM + k0) = v8;
}

// ---------------- normalized latter windows -> WN (f16), md = {mm, mm*den} ----------------
__global__ void build_winn_f16(const float* __restrict__ x, const float* __restrict__ mask,
                               const int* __restrict__ mask_thred_p,
                               _Float16* __restrict__ WN, float2* __restrict__ md, int b0) {
    int b = b0 + blockIdx.z;
    const float* latter = x + (size_t)b * CIN * HW + (size_t)CH * HW;
    const float* maskb = mask + (size_t)b * HW;
    _Float16* WNz = WN + (size_t)blockIdx.z * HW * KDIM;
    float2* mdz = md + (size_t)blockIdx.z * HW;
    int j = blockIdx.x;               // patch index
    int y0 = j >> 6, x0 = j & 63;
    __shared__ float red[256];
    float vals[8];
    float ss = 0.f;
    int k0 = threadIdx.x * 8;
    bool act = (threadIdx.x < 144);
    if (act) {
        #pragma unroll
        for (int u = 0; u < 8; ++u) {
            int k = k0 + u;
            int c = k / 9, q = k - c * 9;
            int dy = q / 3, dx = q - dy * 3;
            int y = y0 + dy - 1, xx = x0 + dx - 1;
            float v = 0.f;
            if ((unsigned)y < H && (unsigned)xx < W) v = latter[c * HW + y * W + xx];
            vals[u] = v;
            ss += v * v;
        }
    }
    red[threadIdx.x] = ss;
    __syncthreads();
    for (int s = 128; s > 0; s >>= 1) {
        if (threadIdx.x < s) red[threadIdx.x] += red[threadIdx.x + s];
        __syncthreads();
    }
    float d = fmaxf(sqrtf(red[0]), 1e-4f);
    float inv = 1.f / d;
    if (act) {
        f16x8 w8;
        #pragma unroll
        for (int u = 0; u < 8; ++u) w8[u] = (_Float16)(vals[u] * inv);
        *(f16x8*)(WNz + (size_t)j * KDIM + k0) = w8;
    }
    if (threadIdx.x == 0) {
        float s = 0.f;
        for (int q = 0; q < 9; ++q) {
            int dy = q / 3, dx = q - dy * 3;
            int y = y0 + dy - 1, xx = x0 + dx - 1;
            if ((unsigned)y < H && (unsigned)xx < W) s += maskb[y * W + xx];
        }
        float mmean = s / 9.f;
        float thr = (float)mask_thred_p[0] / 9.f;
        float m = (mmean <= thr) ? 1.f : 0.f;
        mdz[j] = make_float2(m, m * d);
    }
}

// ---------------- GEMM1: MFMA f16 NT, 128x128 tile, BK=64, XOR LDS, f16 out ----------------
__launch_bounds__(256)
__global__ void gemm_f16_nt(const _Float16* __restrict__ A0, const _Float16* __restrict__ B0,
                            _Float16* __restrict__ C0, int K, int ldc) {
    const _Float16* A = A0 + (size_t)blockIdx.z * HW * KDIM;
    const _Float16* B = B0 + (size_t)blockIdx.z * HW * KDIM;
    _Float16* C = C0 + (size_t)blockIdx.z * HW * HW;
    __shared__ _Float16 As[128 * 64];
    __shared__ _Float16 Bs[128 * 64];
    int tid = threadIdx.x;
    int wave = tid >> 6, lane = tid & 63;
    int quad = lane >> 4, lr = lane & 15;
    int wr = wave >> 1, wc = wave & 1;
    int i0 = blockIdx.y * 128, j0 = blockIdx.x * 128;

    int r0 = tid >> 3;                       // 0..31
    int lk = ((tid & 7) ^ ((tid >> 3) & 7)) * 8;

    f32x4 acc[4][4];
    #pragma unroll
    for (int a = 0; a < 4; ++a)
        #pragma unroll
        for (int b = 0; b < 4; ++b) acc[a][b] = (f32x4){0.f, 0.f, 0.f, 0.f};

    const _Float16* Ab = A + (size_t)i0 * K;
    const _Float16* Bb = B + (size_t)j0 * K;

    int ra[4][2], rb[4][2];
    #pragma unroll
    for (int t = 0; t < 4; ++t) {
        int rowA = wr * 64 + t * 16 + lr;
        int rowB = wc * 64 + t * 16 + lr;
        #pragma unroll
        for (int s = 0; s < 2; ++s) {
            ra[t][s] = rowA * 64 + (((quad + 4 * s) ^ (lr & 7)) * 8);
            rb[t][s] = rowB * 64 + (((quad + 4 * s) ^ (lr & 7)) * 8);
        }
    }

    for (int k0 = 0; k0 < K; k0 += 64) {
        __syncthreads();
        #pragma unroll
        for (int j = 0; j < 4; ++j) {
            int row = r0 + j * 32;
            gl_lds16(Ab + (size_t)row * K + k0 + lk, As + (tid + j * 256) * 8);
            gl_lds16(Bb + (size_t)row * K + k0 + lk, Bs + (tid + j * 256) * 8);
        }
        __syncthreads();
        #pragma unroll
        for (int s = 0; s < 2; ++s) {
            f16x8 af[4], bfr[4];
            #pragma unroll
            for (int mi = 0; mi < 4; ++mi) af[mi] = *(const f16x8*)(As + ra[mi][s]);
            #pragma unroll
            for (int ni = 0; ni < 4; ++ni) bfr[ni] = *(const f16x8*)(Bs + rb[ni][s]);
            #pragma unroll
            for (int mi = 0; mi < 4; ++mi)
                #pragma unroll
                for (int ni = 0; ni < 4; ++ni)
                    acc[mi][ni] = __builtin_amdgcn_mfma_f32_16x16x32_f16(af[mi], bfr[ni], acc[mi][ni], 0, 0, 0);
        }
    }

    #pragma unroll
    for (int mi = 0; mi < 4; ++mi) {
        #pragma unroll
        for (int r = 0; r < 4; ++r) {
            int row = i0 + wr * 64 + mi * 16 + quad * 4 + r;
            _Float16* Cr = C + (size_t)row * ldc + j0 + wc * 64 + lr;
            #pragma unroll
            for (int ni = 0; ni < 4; ++ni)
                Cr[ni * 16] = (_Float16)acc[mi][ni][r];
        }
    }
}

// ---------------- GEMM2: MFMA f16 NT, 128(M)x64(N) tile, BK=64, full K, f16 out ----------------
__launch_bounds__(256)
__global__ void gemm2_f16_nt(const _Float16* __restrict__ A0, const _Float16* __restrict__ B0,
                             _Float16* __restrict__ C0, int K, int ldc) {
    const _Float16* A = A0 + (size_t)blockIdx.z * HW * HW;   // WNT_z (within E1 region)
    const _Float16* B = B0 + (size_t)blockIdx.z * HW * HW;   // YB_z (within S region)
    _Float16* C = C0 + (size_t)blockIdx.z * HW * HW;         // C2T_z (E1 region + KDIM*HW)
    __shared__ _Float16 As[128 * 64];
    __shared__ _Float16 Bs[64 * 64];
    int tid = threadIdx.x;
    int wave = tid >> 6, lane = tid & 63;
    int quad = lane >> 4, lr = lane & 15;
    int wr = wave >> 1, wc = wave & 1;
    int i0 = blockIdx.y * 128, j0 = blockIdx.x * 64;

    int r0 = tid >> 3;
    int lk = ((tid & 7) ^ ((tid >> 3) & 7)) * 8;

    f32x4 acc[4][2];
    #pragma unroll
    for (int a = 0; a < 4; ++a)
        #pragma unroll
        for (int b = 0; b < 2; ++b) acc[a][b] = (f32x4){0.f, 0.f, 0.f, 0.f};

    const _Float16* Ab = A + (size_t)i0 * K;
    const _Float16* Bb = B + (size_t)j0 * K;

    int ra[4][2], rb[2][2];
    #pragma unroll
    for (int t = 0; t < 4; ++t) {
        int rowA = wr * 64 + t * 16 + lr;
        #pragma unroll
        for (int s = 0; s < 2; ++s)
            ra[t][s] = rowA * 64 + (((quad + 4 * s) ^ (lr & 7)) * 8);
    }
    #pragma unroll
    for (int t = 0; t < 2; ++t) {
        int rowB = wc * 32 + t * 16 + lr;
        #pragma unroll
        for (int s = 0; s < 2; ++s)
            rb[t][s] = rowB * 64 + (((quad + 4 * s) ^ (lr & 7)) * 8);
    }

    for (int k0 = 0; k0 < K; k0 += 64) {
        __syncthreads();
        #pragma unroll
        for (int j = 0; j < 4; ++j) {
            int row = r0 + j * 32;
            gl_lds16(Ab + (size_t)row * K + k0 + lk, As + (tid + j * 256) * 8);
        }
        #pragma unroll
        for (int j = 0; j < 2; ++j) {
            int row = r0 + j * 32;
            gl_lds16(Bb + (size_t)row * K + k0 + lk, Bs + (tid + j * 256) * 8);
        }
        __syncthreads();
        #pragma unroll
        for (int s = 0; s < 2; ++s) {
            f16x8 af[4], bfr[2];
            #pragma unroll
            for (int mi = 0; mi < 4; ++mi) af[mi] = *(const f16x8*)(As + ra[mi][s]);
            #pragma unroll
            for (int ni = 0; ni < 2; ++ni) bfr[ni] = *(const f16x8*)(Bs + rb[ni][s]);
            #pragma unroll
            for (int mi = 0; mi < 4; ++mi)
                #pragma unroll
                for (int ni = 0; ni < 2; ++ni)
                    acc[mi][ni] = __builtin_amdgcn_mfma_f32_16x16x32_f16(af[mi], bfr[ni], acc[mi][ni], 0, 0, 0);
        }
    }

    #pragma unroll
    for (int mi = 0; mi < 4; ++mi) {
        #pragma unroll
        for (int r = 0; r < 4; ++r) {
            int row = i0 + wr * 64 + mi * 16 + quad * 4 + r;
            _Float16* Cr = C + (size_t)row * ldc + j0 + wc * 32 + lr;
            #pragma unroll
            for (int ni = 0; ni < 2; ++ni)
                Cr[ni * 16] = (_Float16)acc[mi][ni][r];
        }
    }
}

// ---------------- pass A: 2 output rows/block, 512 thr, f16 in/out, XOR LDS ----------------
__launch_bounds__(512)
__global__ void diag_perm2(const _Float16* __restrict__ S0, _Float16* __restrict__ E10) {
    const _Float16* S = S0 + (size_t)blockIdx.z * HW * HW;
    _Float16* E1 = E10 + (size_t)blockIdx.z * HW * HW;
    int bid = blockIdx.x;                        // 0..2047
    int pair = (bid & 7) * 256 + (bid >> 3);     // XCD-contiguous p ranges
    int p0 = pair * 2;
    int tid = threadIdx.x;
    __shared__ float lds[4][64 * 64];            // 64 KB
    for (int rr = 0; rr < 4; ++rr) {
        int pr = p0 + rr - 1;
        bool v = (unsigned)pr < HW;
        const f16x8* Sr = (const f16x8*)(S + (size_t)pr * HW);
        f16x8 val = v ? Sr[tid] : (f16x8){0, 0, 0, 0, 0, 0, 0, 0};
        int j = tid * 8;
        #pragma unroll
        for (int u = 0; u < 8; ++u) {
            int jj = j + u;
            lds[rr][((jj & 63) << 6) | ((jj >> 6) ^ (jj & 63))] = (float)val[u];
        }
    }
    __syncthreads();
    #pragma unroll
    for (int po = 0; po < 2; ++po) {
        int p = p0 + po;
        int g = ((p & 63) << 6) | (p >> 6);      // rm(p)
        _Float16* Eg = E1 + (size_t)g * HW;
        int h0 = tid * 8;
        f16x8 out;
        #pragma unroll
        for (int u = 0; u < 8; ++u) {
            int h = h0 + u;
            int q = ((h & 63) << 6) | (h >> 6);  // rm(h)
            float s = 0.f;
            #pragma unroll
            for (int d1 = -1; d1 <= 1; ++d1) {
                int pp = p + d1, qq = q + d1;
                if ((unsigned)pp < HW && (unsigned)qq < HW)
                    s += lds[po + d1 + 1][((qq & 63) << 6) | ((qq >> 6) ^ (qq & 63))];
            }
            out[u] = (_Float16)s;
        }
        *(f16x8*)(Eg + h0) = out;
    }
}

// ---------------- pass B: D2 = diagbox3(E1); softmax over h; *mm*den; f16 out ----------------
__launch_bounds__(512)
__global__ void diag_softmax(const _Float16* __restrict__ E10, const float2* __restrict__ md0,
                             _Float16* __restrict__ YB0) {
    const _Float16* E1 = E10 + (size_t)blockIdx.z * HW * HW;
    const float2* md = md0 + (size_t)blockIdx.z * HW;
    _Float16* YB = YB0 + (size_t)blockIdx.z * HW * HW;
    int g = (blockIdx.x & 7) * 512 + (blockIdx.x >> 3);   // XCD-contiguous g ranges
    int tid = threadIdx.x;
    int h0 = tid * 8;
    __shared__ float red[512];
    float D[8] = {0.f, 0.f, 0.f, 0.f, 0.f, 0.f, 0.f, 0.f};
    #pragma unroll
    for (int d2 = -1; d2 <= 1; ++d2) {
        int gg = g + d2;
        if ((unsigned)gg >= HW) continue;
        const _Float16* Er = E1 + (size_t)gg * HW;
        float w[10];  // covers indices h0-1 .. h0+8
        f16x8 m8 = *(const f16x8*)(Er + h0);
        #pragma unroll
        for (int u = 0; u < 8; ++u) w[u + 1] = (float)m8[u];
        w[0] = (h0 > 0) ? (float)Er[h0 - 1] : 0.f;
        w[9] = (h0 + 8 < HW) ? (float)Er[h0 + 8] : 0.f;
        #pragma unroll
        for (int u = 0; u < 8; ++u) {
            int hh = h0 + u + d2;
            if ((unsigned)hh < HW) D[u] += w[u + d2 + 1];
        }
    }
    float lv[8], sv[8];
    float lmax = -1e30f;
    #pragma unroll
    for (int u = 0; u < 8; ++u) {
        int h = h0 + u;
        int j = ((h & 63) << 6) | (h >> 6);  // rm(h)
        float2 m2 = md[j];
        float l = 10.f * D[u] * m2.x;
        lv[u] = l;
        sv[u] = m2.y;
        lmax = fmaxf(lmax, l);
    }
    red[tid] = lmax;
    __syncthreads();
    for (int s = 256; s > 0; s >>= 1) {
        if (tid < s) red[tid] = fmaxf(red[tid], red[tid + s]);
        __syncthreads();
    }
    float M = red[0];
    __syncthreads();
    float ev[8];
    float ssum = 0.f;
    #pragma unroll
    for (int u = 0; u < 8; ++u) {
        ev[u] = expf(lv[u] - M);
        ssum += ev[u];
    }
    red[tid] = ssum;
    __syncthreads();
    for (int s = 256; s > 0; s >>= 1) {
        if (tid < s) red[tid] += red[tid + s];
        __syncthreads();
    }
    float inv = 1.f / red[0];
    f16x8 outv;
    #pragma unroll
    for (int u = 0; u < 8; ++u)
        outv[u] = (_Float16)(ev[u] * inv * sv[u]);
    *(f16x8*)(YB + (size_t)g * HW + h0) = outv;
}

// ---------------- WNT[n, h] = WN[rm(h)][n]  (f16, K-contiguous for GEMM2) ----------------
__launch_bounds__(256)
__global__ void wnt_transpose(const _Float16* __restrict__ WN0, _Float16* __restrict__ WNT0) {
    const _Float16* WN = WN0 + (size_t)blockIdx.z * HW * KDIM;
    _Float16* WNT = WNT0 + (size_t)blockIdx.z * HW * HW;
    int bx = blockIdx.x;  // h-tile: h = bx*64 + l -> j = l*64 + bx
    int by = blockIdx.y;  // n-tile
    int n0 = by * 64;
    __shared__ unsigned short tile[64][72];
    for (int c = threadIdx.x; c < 512; c += 256) {
        int l = c >> 3, seg = c & 7;
        int j = l * 64 + bx;
        uint4 v = *(const uint4*)(WN + (size_t)j * KDIM + n0 + seg * 8);
        *(uint4*)&tile[l][seg * 8] = v;
    }
    __syncthreads();
    for (int c = threadIdx.x; c < 512; c += 256) {
        int r = c >> 3, seg = c & 7;
        unsigned short tmp[8];
        #pragma unroll
        for (int u = 0; u < 8; ++u) tmp[u] = tile[seg * 8 + u][r];
        *(uint4*)(WNT + (size_t)(n0 + r) * HW + bx * 64 + seg * 8) = *(uint4*)tmp;
    }
}

// ---------------- fold C2T f16 (KDIM x HW, cols g = x*64+y) into shift output ----------------
__launch_bounds__(256)
__global__ void fold_out_t(const _Float16* __restrict__ C2T0, float* __restrict__ out, int b0) {
    const _Float16* C2T = C2T0 + (size_t)blockIdx.z * HW * HW;
    float* outb = out + (size_t)(b0 + blockIdx.z) * COUT * HW;
    int c = blockIdx.x;
    __shared__ float lds[64 * 65];
    const _Float16* base = C2T + (size_t)c * 9 * HW;
    #pragma unroll 4
    for (int t = 0; t < 16; ++t) {
        int pos = threadIdx.x + t * 256;
        int x = pos >> 6, y = pos & 63;
        float s = 0.f;
        #pragma unroll
        for (int dy = 0; dy < 3; ++dy) {
            int yy = y + 1 - dy;
            if ((unsigned)yy >= 64) continue;
            #pragma unroll
            for (int dx = 0; dx < 3; ++dx) {
                int xx = x + 1 - dx;
                if ((unsigned)xx >= 64) continue;
                s += (float)base[(size_t)(dy * 3 + dx) * HW + xx * 64 + yy];
            }
        }
        lds[y * 65 + x] = s * (1.f / 9.f);
    }
    __syncthreads();
    #pragma unroll 4
    for (int t = 0; t < 16; ++t) {
        int pix = threadIdx.x + t * 256;
        outb[(size_t)(CIN + c) * HW + pix] = lds[(pix >> 6) * 65 + (pix & 63)];
    }
}

extern "C" void kernel_launch(void* const* d_in, const int* in_sizes, int n_in,
                              void* d_out, int out_size, void* d_ws, size_t ws_size,
                              hipStream_t stream) {
    const float* x = (const float*)d_in[0];
    const float* mask = (const float*)d_in[1];
    const int* mask_thred = (const int*)d_in[3];
    float* out = (float*)d_out;

    char* ws = (char*)d_ws;
    _Float16* P   = (_Float16*)(ws);                      // 2 x  9,437,184 B
    _Float16* WN  = (_Float16*)(ws + 18874368);           // 2 x  9,437,184 B
    _Float16* S   = (_Float16*)(ws + 37748736);           // 2 x 33,554,432 B (scores, then YB)
    _Float16* E1r = (_Float16*)(ws + 104857600);          // 2 x 33,554,432 B (E1, then WNT+C2T)
    float2*   md  = (float2*)(ws + 171966464);            // 2 x 32,768 B
    // per-z aliases inside E1 region (E1 dead after softmax):
    _Float16* WNT = E1r;                                  // z-stride HW*HW, size KDIM*HW
    _Float16* C2T = E1r + (size_t)KDIM * HW;              // z-stride HW*HW, size KDIM*HW
    _Float16* YB  = S;                                    // z-stride HW*HW

    copy_passthrough<<<(NB * CIN * HW / 4 + 255) / 256, 256, 0, stream>>>((const float4*)x, (float4*)out);

    for (int pp = 0; pp < 2; ++pp) {
        int b0 = pp * 2;
        build_patches_f16<<<dim3((HW * 144 + 255) / 256, 1, 2), 256, 0, stream>>>(x, P, b0);
        build_winn_f16<<<dim3(HW, 1, 2), 256, 0, stream>>>(x, mask, mask_thred, WN, md, b0);
        gemm_f16_nt<<<dim3(32, 32, 2), 256, 0, stream>>>(P, WN, S, KDIM, HW);
        diag_perm2<<<dim3(HW / 2, 1, 2), 512, 0, stream>>>(S, E1r);
        diag_softmax<<<dim3(HW, 1, 2), 512, 0, stream>>>(E1r, md, YB);
        wnt_transpose<<<dim3(64, KDIM / 64, 2), 256, 0, stream>>>(WN, WNT);
        // C2T[n][g] = sum_h WNT[n][h] * YB[g][h]  (M=1152, N=4096, K=4096) per z
        gemm2_f16_nt<<<dim3(64, KDIM / 128, 2), 256, 0, stream>>>(WNT, YB, C2T, HW, HW);
        fold_out_t<<<dim3(CH, 1, 2), 256, 0, stream>>>(C2T, out, b0);
    }
}

// Round 11
// 801.221 us; speedup vs baseline: 1.5310x; 1.1285x over previous
//
#include <hip/hip_runtime.h>
#include <math.h>

#define H 64
#define W 64
#define HW 4096
#define CH 128
#define CIN 256
#define COUT 384
#define KDIM 1152
#define NB 4

typedef _Float16 f16x8 __attribute__((ext_vector_type(8)));
typedef float f32x4 __attribute__((ext_vector_type(4)));

__device__ __forceinline__ void gl_lds16(const _Float16* g, _Float16* l) {
    __builtin_amdgcn_global_load_lds(
        (const __attribute__((address_space(1))) unsigned int*)(g),
        (__attribute__((address_space(3))) unsigned int*)(l), 16, 0, 0);
}

// ---------------- copy former+latter passthrough (float4) ----------------
__global__ void copy_passthrough(const float4* __restrict__ x, float4* __restrict__ out) {
    int idx = blockIdx.x * blockDim.x + threadIdx.x; // over NB*CIN*HW/4
    if (idx >= NB * CIN * HW / 4) return;
    int b = idx / (CIN * HW / 4);
    int rem = idx - b * (CIN * HW / 4);
    out[(size_t)b * (COUT * HW / 4) + rem] = x[idx];
}

// ---------------- im2col of former -> P (HW x KDIM, f16), z = sample in pair ----------------
__global__ void build_patches_f16(const float* __restrict__ x, _Float16* __restrict__ P, int b0) {
    int idx8 = blockIdx.x * blockDim.x + threadIdx.x; // over HW*144
    if (idx8 >= HW * 144) return;
    const float* former = x + (size_t)(b0 + blockIdx.z) * CIN * HW;
    _Float16* Pz = P + (size_t)blockIdx.z * HW * KDIM;
    int i = idx8 / 144, k0 = (idx8 - i * 144) * 8;
    int iy = i >> 6, ix = i & 63;
    f16x8 v8;
    #pragma unroll
    for (int u = 0; u < 8; ++u) {
        int k = k0 + u;
        int c = k / 9, q = k - c * 9;
        int dy = q / 3, dx = q - dy * 3;
        int y = iy + dy - 1, xx = ix + dx - 1;
        float v = 0.f;
        if ((unsigned)y < H && (unsigned)xx < W) v = former[c * HW + y * W + xx];
        v8[u] = (_Float16)v;
    }
    *(f16x8*)(Pz + (size_t)i * KDIM + k0) = v8;
}

// ---------------- normalized latter windows -> WN (f16), md = {mm, mm*den} ----------------
__global__ void build_winn_f16(const float* __restrict__ x, const float* __restrict__ mask,
                               const int* __restrict__ mask_thred_p,
                               _Float16* __restrict__ WN, float2* __restrict__ md, int b0) {
    int b = b0 + blockIdx.z;
    const float* latter = x + (size_t)b * CIN * HW + (size_t)CH * HW;
    const float* maskb = mask + (size_t)b * HW;
    _Float16* WNz = WN + (size_t)blockIdx.z * HW * KDIM;
    float2* mdz = md + (size_t)blockIdx.z * HW;
    int j = blockIdx.x;               // patch index (row-major)
    int y0 = j >> 6, x0 = j & 63;
    __shared__ float red[256];
    float vals[8];
    float ss = 0.f;
    int k0 = threadIdx.x * 8;
    bool act = (threadIdx.x < 144);
    if (act) {
        #pragma unroll
        for (int u = 0; u < 8; ++u) {
            int k = k0 + u;
            int c = k / 9, q = k - c * 9;
            int dy = q / 3, dx = q - dy * 3;
            int y = y0 + dy - 1, xx = x0 + dx - 1;
            float v = 0.f;
            if ((unsigned)y < H && (unsigned)xx < W) v = latter[c * HW + y * W + xx];
            vals[u] = v;
            ss += v * v;
        }
    }
    red[threadIdx.x] = ss;
    __syncthreads();
    for (int s = 128; s > 0; s >>= 1) {
        if (threadIdx.x < s) red[threadIdx.x] += red[threadIdx.x + s];
        __syncthreads();
    }
    float d = fmaxf(sqrtf(red[0]), 1e-4f);
    float inv = 1.f / d;
    if (act) {
        f16x8 w8;
        #pragma unroll
        for (int u = 0; u < 8; ++u) w8[u] = (_Float16)(vals[u] * inv);
        *(f16x8*)(WNz + (size_t)j * KDIM + k0) = w8;
    }
    if (threadIdx.x == 0) {
        float s = 0.f;
        for (int q = 0; q < 9; ++q) {
            int dy = q / 3, dx = q - dy * 3;
            int y = y0 + dy - 1, xx = x0 + dx - 1;
            if ((unsigned)y < H && (unsigned)xx < W) s += maskb[y * W + xx];
        }
        float mmean = s / 9.f;
        float thr = (float)mask_thred_p[0] / 9.f;
        float m = (mmean <= thr) ? 1.f : 0.f;
        mdz[j] = make_float2(m, m * d);
    }
}

// ---------------- GEMM1: MFMA f16 NT, 128x128 tile, BK=64, XOR LDS, f16 out ----------------
__launch_bounds__(256)
__global__ void gemm_f16_nt(const _Float16* __restrict__ A0, const _Float16* __restrict__ B0,
                            _Float16* __restrict__ C0, int K, int ldc) {
    const _Float16* A = A0 + (size_t)blockIdx.z * HW * KDIM;
    const _Float16* B = B0 + (size_t)blockIdx.z * HW * KDIM;
    _Float16* C = C0 + (size_t)blockIdx.z * HW * HW;
    __shared__ _Float16 As[128 * 64];
    __shared__ _Float16 Bs[128 * 64];
    int tid = threadIdx.x;
    int wave = tid >> 6, lane = tid & 63;
    int quad = lane >> 4, lr = lane & 15;
    int wr = wave >> 1, wc = wave & 1;
    int i0 = blockIdx.y * 128, j0 = blockIdx.x * 128;

    int r0 = tid >> 3;                       // 0..31
    int lk = ((tid & 7) ^ ((tid >> 3) & 7)) * 8;

    f32x4 acc[4][4];
    #pragma unroll
    for (int a = 0; a < 4; ++a)
        #pragma unroll
        for (int b = 0; b < 4; ++b) acc[a][b] = (f32x4){0.f, 0.f, 0.f, 0.f};

    const _Float16* Ab = A + (size_t)i0 * K;
    const _Float16* Bb = B + (size_t)j0 * K;

    int ra[4][2], rb[4][2];
    #pragma unroll
    for (int t = 0; t < 4; ++t) {
        int rowA = wr * 64 + t * 16 + lr;
        int rowB = wc * 64 + t * 16 + lr;
        #pragma unroll
        for (int s = 0; s < 2; ++s) {
            ra[t][s] = rowA * 64 + (((quad + 4 * s) ^ (lr & 7)) * 8);
            rb[t][s] = rowB * 64 + (((quad + 4 * s) ^ (lr & 7)) * 8);
        }
    }

    for (int k0 = 0; k0 < K; k0 += 64) {
        __syncthreads();
        #pragma unroll
        for (int j = 0; j < 4; ++j) {
            int row = r0 + j * 32;
            gl_lds16(Ab + (size_t)row * K + k0 + lk, As + (tid + j * 256) * 8);
            gl_lds16(Bb + (size_t)row * K + k0 + lk, Bs + (tid + j * 256) * 8);
        }
        __syncthreads();
        #pragma unroll
        for (int s = 0; s < 2; ++s) {
            f16x8 af[4], bfr[4];
            #pragma unroll
            for (int mi = 0; mi < 4; ++mi) af[mi] = *(const f16x8*)(As + ra[mi][s]);
            #pragma unroll
            for (int ni = 0; ni < 4; ++ni) bfr[ni] = *(const f16x8*)(Bs + rb[ni][s]);
            #pragma unroll
            for (int mi = 0; mi < 4; ++mi)
                #pragma unroll
                for (int ni = 0; ni < 4; ++ni)
                    acc[mi][ni] = __builtin_amdgcn_mfma_f32_16x16x32_f16(af[mi], bfr[ni], acc[mi][ni], 0, 0, 0);
        }
    }

    #pragma unroll
    for (int mi = 0; mi < 4; ++mi) {
        #pragma unroll
        for (int r = 0; r < 4; ++r) {
            int row = i0 + wr * 64 + mi * 16 + quad * 4 + r;
            _Float16* Cr = C + (size_t)row * ldc + j0 + wc * 64 + lr;
            #pragma unroll
            for (int ni = 0; ni < 4; ++ni)
                Cr[ni * 16] = (_Float16)acc[mi][ni][r];
        }
    }
}

// ---------------- GEMM2: MFMA f16 NT, 128(M)x64(N) tile, BK=64, full K, f16 out ----------------
__launch_bounds__(256)
__global__ void gemm2_f16_nt(const _Float16* __restrict__ A0, const _Float16* __restrict__ B0,
                             _Float16* __restrict__ C0, int K, int ldc) {
    const _Float16* A = A0 + (size_t)blockIdx.z * HW * HW;   // WNT_z
    const _Float16* B = B0 + (size_t)blockIdx.z * HW * HW;   // V_z
    _Float16* C = C0 + (size_t)blockIdx.z * HW * HW;         // C2T_z
    __shared__ _Float16 As[128 * 64];
    __shared__ _Float16 Bs[64 * 64];
    int tid = threadIdx.x;
    int wave = tid >> 6, lane = tid & 63;
    int quad = lane >> 4, lr = lane & 15;
    int wr = wave >> 1, wc = wave & 1;
    int i0 = blockIdx.y * 128, j0 = blockIdx.x * 64;

    int r0 = tid >> 3;
    int lk = ((tid & 7) ^ ((tid >> 3) & 7)) * 8;

    f32x4 acc[4][2];
    #pragma unroll
    for (int a = 0; a < 4; ++a)
        #pragma unroll
        for (int b = 0; b < 2; ++b) acc[a][b] = (f32x4){0.f, 0.f, 0.f, 0.f};

    const _Float16* Ab = A + (size_t)i0 * K;
    const _Float16* Bb = B + (size_t)j0 * K;

    int ra[4][2], rb[2][2];
    #pragma unroll
    for (int t = 0; t < 4; ++t) {
        int rowA = wr * 64 + t * 16 + lr;
        #pragma unroll
        for (int s = 0; s < 2; ++s)
            ra[t][s] = rowA * 64 + (((quad + 4 * s) ^ (lr & 7)) * 8);
    }
    #pragma unroll
    for (int t = 0; t < 2; ++t) {
        int rowB = wc * 32 + t * 16 + lr;
        #pragma unroll
        for (int s = 0; s < 2; ++s)
            rb[t][s] = rowB * 64 + (((quad + 4 * s) ^ (lr & 7)) * 8);
    }

    for (int k0 = 0; k0 < K; k0 += 64) {
        __syncthreads();
        #pragma unroll
        for (int j = 0; j < 4; ++j) {
            int row = r0 + j * 32;
            gl_lds16(Ab + (size_t)row * K + k0 + lk, As + (tid + j * 256) * 8);
        }
        #pragma unroll
        for (int j = 0; j < 2; ++j) {
            int row = r0 + j * 32;
            gl_lds16(Bb + (size_t)row * K + k0 + lk, Bs + (tid + j * 256) * 8);
        }
        __syncthreads();
        #pragma unroll
        for (int s = 0; s < 2; ++s) {
            f16x8 af[4], bfr[2];
            #pragma unroll
            for (int mi = 0; mi < 4; ++mi) af[mi] = *(const f16x8*)(As + ra[mi][s]);
            #pragma unroll
            for (int ni = 0; ni < 2; ++ni) bfr[ni] = *(const f16x8*)(Bs + rb[ni][s]);
            #pragma unroll
            for (int mi = 0; mi < 4; ++mi)
                #pragma unroll
                for (int ni = 0; ni < 2; ++ni)
                    acc[mi][ni] = __builtin_amdgcn_mfma_f32_16x16x32_f16(af[mi], bfr[ni], acc[mi][ni], 0, 0, 0);
        }
    }

    #pragma unroll
    for (int mi = 0; mi < 4; ++mi) {
        #pragma unroll
        for (int r = 0; r < 4; ++r) {
            int row = i0 + wr * 64 + mi * 16 + quad * 4 + r;
            _Float16* Cr = C + (size_t)row * ldc + j0 + wc * 32 + lr;
            #pragma unroll
            for (int ni = 0; ni < 2; ++ni)
                Cr[ni * 16] = (_Float16)acc[mi][ni][r];
        }
    }
}

// ---------------- zconv: Zc[p][q] = sum_{d1} S[p+d1][q+d1] (flat bounds), pure streaming ----------------
__launch_bounds__(512)
__global__ void zconv(const _Float16* __restrict__ S0, _Float16* __restrict__ Z0) {
    const _Float16* S = S0 + (size_t)blockIdx.z * HW * HW;
    _Float16* Z = Z0 + (size_t)blockIdx.z * HW * HW;
    int p = (blockIdx.x & 7) * 512 + (blockIdx.x >> 3);   // XCD-contiguous p ranges
    int tid = threadIdx.x;
    int q0 = tid * 8;
    float acc[8] = {0.f, 0.f, 0.f, 0.f, 0.f, 0.f, 0.f, 0.f};
    #pragma unroll
    for (int d1 = -1; d1 <= 1; ++d1) {
        int pr = p + d1;
        if ((unsigned)pr >= HW) continue;
        const _Float16* Sr = S + (size_t)pr * HW;
        f16x8 v = *(const f16x8*)(Sr + q0);
        if (d1 == 0) {
            #pragma unroll
            for (int u = 0; u < 8; ++u) acc[u] += (float)v[u];
        } else if (d1 == 1) {
            // need cols q0+1..q0+8
            #pragma unroll
            for (int u = 0; u < 7; ++u) acc[u] += (float)v[u + 1];
            if (q0 + 8 < HW) acc[7] += (float)Sr[q0 + 8];
        } else {
            // need cols q0-1..q0+6
            #pragma unroll
            for (int u = 1; u < 8; ++u) acc[u] += (float)v[u - 1];
            if (q0 > 0) acc[0] += (float)Sr[q0 - 1];
        }
    }
    f16x8 out;
    #pragma unroll
    for (int u = 0; u < 8; ++u) out[u] = (_Float16)acc[u];
    *(f16x8*)(Z + (size_t)p * HW + q0) = out;
}

// ---------------- softmax2: W2 = perm-space diagbox64(Zc) + boundary fixups; softmax over q; f16 V ----------------
// D2[p][q] = Zc[p][q] + (valid d2=+1) Zc[P1][Q1(q)] + (valid d2=-1) Zc[P0][Q0(q)]
// P1 = p+64 (p>>6<63) else (p&63)+1; valid iff p != 4095
// P0 = p-64 (p>>6>0) else 4031+(p&63); valid iff p != 0
// Q1 = q+64 (q>>6<63) else (q&63)+1; valid iff q != 4095
// Q0 = q-64 (q>>6>0) else 4031+(q&63); valid iff q != 0
__launch_bounds__(512)
__global__ void softmax2(const _Float16* __restrict__ Z0, const float2* __restrict__ md0,
                         _Float16* __restrict__ V0) {
    const _Float16* Z = Z0 + (size_t)blockIdx.z * HW * HW;
    const float2* md = md0 + (size_t)blockIdx.z * HW;
    _Float16* V = V0 + (size_t)blockIdx.z * HW * HW;
    int p = (blockIdx.x & 7) * 512 + (blockIdx.x >> 3);   // XCD-contiguous p ranges
    int tid = threadIdx.x;
    int q0 = tid * 8;
    __shared__ float red[512];
    float D[8];
    {
        f16x8 a = *(const f16x8*)(Z + (size_t)p * HW + q0);
        #pragma unroll
        for (int u = 0; u < 8; ++u) D[u] = (float)a[u];
    }
    if (p != 4095) {                                   // d2 = +1
        int P1 = ((p >> 6) < 63) ? (p + 64) : ((p & 63) + 1);
        const _Float16* Zr = Z + (size_t)P1 * HW;
        if ((tid >> 3) != 63) {
            f16x8 b = *(const f16x8*)(Zr + q0 + 64);
            #pragma unroll
            for (int u = 0; u < 8; ++u) D[u] += (float)b[u];
        } else {
            #pragma unroll
            for (int u = 0; u < 8; ++u) {
                int q = q0 + u;
                if (q != 4095) D[u] += (float)Zr[(q & 63) + 1];
            }
        }
    }
    if (p != 0) {                                      // d2 = -1
        int P0 = ((p >> 6) > 0) ? (p - 64) : (4031 + (p & 63));
        const _Float16* Zr = Z + (size_t)P0 * HW;
        if ((tid >> 3) != 0) {
            f16x8 b = *(const f16x8*)(Zr + q0 - 64);
            #pragma unroll
            for (int u = 0; u < 8; ++u) D[u] += (float)b[u];
        } else {
            #pragma unroll
            for (int u = 0; u < 8; ++u) {
                int q = q0 + u;
                if (q != 0) D[u] += (float)Zr[4031 + q];
            }
        }
    }
    float lv[8], sv[8];
    float lmax = -1e30f;
    #pragma unroll
    for (int u = 0; u < 8; ++u) {
        float2 m2 = md[q0 + u];
        float l = 10.f * D[u] * m2.x;
        lv[u] = l;
        sv[u] = m2.y;
        lmax = fmaxf(lmax, l);
    }
    red[tid] = lmax;
    __syncthreads();
    for (int s = 256; s > 0; s >>= 1) {
        if (tid < s) red[tid] = fmaxf(red[tid], red[tid + s]);
        __syncthreads();
    }
    float M = red[0];
    __syncthreads();
    float ev[8];
    float ssum = 0.f;
    #pragma unroll
    for (int u = 0; u < 8; ++u) {
        ev[u] = expf(lv[u] - M);
        ssum += ev[u];
    }
    red[tid] = ssum;
    __syncthreads();
    for (int s = 256; s > 0; s >>= 1) {
        if (tid < s) red[tid] += red[tid + s];
        __syncthreads();
    }
    float inv = 1.f / red[0];
    f16x8 outv;
    #pragma unroll
    for (int u = 0; u < 8; ++u)
        outv[u] = (_Float16)(ev[u] * inv * sv[u]);
    *(f16x8*)(V + (size_t)p * HW + q0) = outv;
}

// ---------------- WNT[n, j] = WN[j][n]  (plain transpose, f16) ----------------
__launch_bounds__(256)
__global__ void wnt_transpose(const _Float16* __restrict__ WN0, _Float16* __restrict__ WNT0) {
    const _Float16* WN = WN0 + (size_t)blockIdx.z * HW * KDIM;
    _Float16* WNT = WNT0 + (size_t)blockIdx.z * HW * HW;
    int bx = blockIdx.x;  // j-tile
    int by = blockIdx.y;  // n-tile
    int n0 = by * 64;
    __shared__ unsigned short tile[64][72];
    for (int c = threadIdx.x; c < 512; c += 256) {
        int l = c >> 3, seg = c & 7;
        int j = bx * 64 + l;
        uint4 v = *(const uint4*)(WN + (size_t)j * KDIM + n0 + seg * 8);
        *(uint4*)&tile[l][seg * 8] = v;
    }
    __syncthreads();
    for (int c = threadIdx.x; c < 512; c += 256) {
        int r = c >> 3, seg = c & 7;
        unsigned short tmp[8];
        #pragma unroll
        for (int u = 0; u < 8; ++u) tmp[u] = tile[seg * 8 + u][r];
        *(uint4*)(WNT + (size_t)(n0 + r) * HW + bx * 64 + seg * 8) = *(uint4*)tmp;
    }
}

// ---------------- fold C2T f16 (KDIM x HW, cols p = y*64+x row-major) into shift output ----------------
__launch_bounds__(256)
__global__ void fold_out_t(const _Float16* __restrict__ C2T0, float* __restrict__ out, int b0) {
    const _Float16* C2T = C2T0 + (size_t)blockIdx.z * HW * HW;
    float* outb = out + (size_t)(b0 + blockIdx.z) * COUT * HW;
    int c = blockIdx.x;
    const _Float16* base = C2T + (size_t)c * 9 * HW;
    #pragma unroll 4
    for (int t = 0; t < 16; ++t) {
        int pix = threadIdx.x + t * 256;   // pix = y*64 + x
        int y = pix >> 6, x = pix & 63;
        float s = 0.f;
        #pragma unroll
        for (int dy = 0; dy < 3; ++dy) {
            int yy = y + 1 - dy;
            if ((unsigned)yy >= 64) continue;
            #pragma unroll
            for (int dx = 0; dx < 3; ++dx) {
                int xx = x + 1 - dx;
                if ((unsigned)xx >= 64) continue;
                s += (float)base[(size_t)(dy * 3 + dx) * HW + yy * 64 + xx];
            }
        }
        outb[(size_t)(CIN + c) * HW + pix] = s * (1.f / 9.f);
    }
}

extern "C" void kernel_launch(void* const* d_in, const int* in_sizes, int n_in,
                              void* d_out, int out_size, void* d_ws, size_t ws_size,
                              hipStream_t stream) {
    const float* x = (const float*)d_in[0];
    const float* mask = (const float*)d_in[1];
    const int* mask_thred = (const int*)d_in[3];
    float* out = (float*)d_out;

    char* ws = (char*)d_ws;
    _Float16* P   = (_Float16*)(ws);                      // 2 x  9,437,184 B
    _Float16* WN  = (_Float16*)(ws + 18874368);           // 2 x  9,437,184 B
    _Float16* S   = (_Float16*)(ws + 37748736);           // 2 x 33,554,432 B (scores, then V)
    _Float16* Zc  = (_Float16*)(ws + 104857600);          // 2 x 33,554,432 B (Zc, then WNT+C2T)
    float2*   md  = (float2*)(ws + 171966464);            // 2 x 32,768 B
    // aliases (lifetimes disjoint, per-z stride HW*HW):
    _Float16* V   = S;                                    // softmax output over scores region
    _Float16* WNT = Zc;                                   // plain-transposed WN
    _Float16* C2T = Zc + (size_t)KDIM * HW;               // gemm2 output

    copy_passthrough<<<(NB * CIN * HW / 4 + 255) / 256, 256, 0, stream>>>((const float4*)x, (float4*)out);

    for (int pp = 0; pp < 2; ++pp) {
        int b0 = pp * 2;
        build_patches_f16<<<dim3((HW * 144 + 255) / 256, 1, 2), 256, 0, stream>>>(x, P, b0);
        build_winn_f16<<<dim3(HW, 1, 2), 256, 0, stream>>>(x, mask, mask_thred, WN, md, b0);
        gemm_f16_nt<<<dim3(32, 32, 2), 256, 0, stream>>>(P, WN, S, KDIM, HW);
        zconv<<<dim3(HW, 1, 2), 512, 0, stream>>>(S, Zc);
        softmax2<<<dim3(HW, 1, 2), 512, 0, stream>>>(Zc, md, V);
        wnt_transpose<<<dim3(64, KDIM / 64, 2), 256, 0, stream>>>(WN, WNT);
        // C2T[n][p] = sum_q WNT[n][q] * V[p][q]  (M=1152, N=4096, K=4096) per z
        gemm2_f16_nt<<<dim3(64, KDIM / 128, 2), 256, 0, stream>>>(WNT, V, C2T, HW, HW);
        fold_out_t<<<dim3(CH, 1, 2), 256, 0, stream>>>(C2T, out, b0);
    }
}